// Round 1
// baseline (278.747 us; speedup 1.0000x reference)
//
#include <hip/hip_runtime.h>

typedef _Float16 half8  __attribute__((ext_vector_type(8)));
typedef _Float16 half4  __attribute__((ext_vector_type(4)));
typedef float    float4v __attribute__((ext_vector_type(4)));
typedef float    float8v __attribute__((ext_vector_type(8)));

#define N_ROWS  65536   // 64*32*32
#define N_CODES 1024
#define DIM     256
#define BM      128     // rows per block
#define NBLKS   (N_ROWS / BM)   // 512

// ---- prep: one wave per code. ||e||^2 and hi/lo f16 split written in MFMA
// B-fragment order: frag block b = nt*8 + ks holds 1024 halves: [hi 512][lo 512],
// chunk p = quad*16 + l15 -> code = nt*16+l15, k = ks*32 + quad*8 + j.
__global__ __launch_bounds__(64)
void vq_prep(const float* __restrict__ emb, float* __restrict__ e_norm,
             _Float16* __restrict__ e_frag) {
    const int c = blockIdx.x, lane = threadIdx.x;
    const int l15 = c & 15, nt = c >> 4;
    float4v v = ((const float4v*)(emb + (size_t)c * DIM))[lane];
    half4 h, l;
    float ss = 0.f;
    #pragma unroll
    for (int j = 0; j < 4; ++j) {
        float x = v[j];
        ss += x * x;
        _Float16 hh = (_Float16)x;
        h[j] = hh;
        l[j] = (_Float16)(x - (float)hh);
    }
    // this lane's 4 elements: k = lane*4 .. +3
    const int ks = lane >> 3, q = (lane >> 1) & 3, jb = (lane & 1) * 4;
    _Float16* p = e_frag + ((size_t)(nt * 8 + ks)) * 1024 + (q * 16 + l15) * 8 + jb;
    *(half4*)p = h;
    *(half4*)(p + 512) = l;
    #pragma unroll
    for (int m = 32; m >= 1; m >>= 1) ss += __shfl_xor(ss, m, 64);
    if (lane == 0) e_norm[c] = ss;
}

// ---- main: 512 threads (8 waves), BM=128 rows/block, full K in LDS,
// ONE staging barrier. Wave w handles codes [w*128, w*128+128) in 4 passes
// of 32 codes (acc[8][2] = 64 AGPRs, freeing regs for a double-buffered
// B prefetch). B-frags double-buffered from global (L2-resident), ks loop
// fully unrolled so prefetch regs stay static. Fused argmin + gather.
__global__ __launch_bounds__(512, 2)
void vq_main(const float* __restrict__ z,
             const _Float16* __restrict__ e_frag,
             const float* __restrict__ e_norm,
             const float* __restrict__ emb,
             float* __restrict__ zq,
             float* __restrict__ idxf,
             int fused_gather) {
    __shared__ _Float16 sA[64 * 2 * 512];     // [mt*8+ks][hi|lo][512] = 128 KB
    __shared__ float    s_nrm[N_CODES];       // 4 KB
    __shared__ float2   s_best[BM][9];        // 8 wave slots + pad: 9 KB
    __shared__ int      s_idx[BM];

    const int t = threadIdx.x;
    const int w = t >> 6, lane = t & 63, quad = lane >> 4, l15 = lane & 15;
    const int rowblk = blockIdx.x * BM;

    s_nrm[t] = e_norm[t];
    s_nrm[t + 512] = e_norm[t + 512];

    // ---- B prefetch for pass 0 / ks 0 (pure global, no LDS dependency:
    // issue before the staging barrier so latency hides under staging).
    half8 bh[2][2], bl[2][2];
    {
        const int ntbase0 = w * 8;
        #pragma unroll
        for (int nt = 0; nt < 2; ++nt) {
            const _Float16* bp = e_frag + ((size_t)((ntbase0 + nt) * 8 + 0)) * 1024 + lane * 8;
            bh[0][nt] = *(const half8*)bp;
            bl[0][nt] = *(const half8*)(bp + 512);
        }
    }

    // ---- stage A: full K, hi/lo f16, fragment order, lane-linear LDS writes.
    // wave w stages ks=w for mt=i: global = 16 rows x 128 B contiguous chunks;
    // LDS write addr = fragbase + lane*16 (conflict-free).
    #pragma unroll
    for (int i = 0; i < 8; ++i) {
        const int mt = i, ks = w;
        const int row = mt * 16 + l15;
        const int col = ks * 32 + quad * 8;
        float8v v = *(const float8v*)(z + (size_t)(rowblk + row) * DIM + col);
        half8 h, lo;
        #pragma unroll
        for (int j = 0; j < 8; ++j) {
            float x = v[j];
            _Float16 hh = (_Float16)x;
            h[j] = hh;
            lo[j] = (_Float16)(x - (float)hh);
        }
        _Float16* p = sA + (size_t)((mt * 8 + ks) * 2) * 512 + lane * 8;
        *(half8*)p = h;
        *(half8*)(p + 512) = lo;
    }
    __syncthreads();   // the only compute barrier

    for (int pass = 0; pass < 4; ++pass) {
        const int ntbase = w * 8 + pass * 2;

        // refill buf0 with this pass's ks=0 frags (pass 0 was preloaded)
        if (pass) {
            #pragma unroll
            for (int nt = 0; nt < 2; ++nt) {
                const _Float16* bp = e_frag + ((size_t)((ntbase + nt) * 8 + 0)) * 1024 + lane * 8;
                bh[0][nt] = *(const half8*)bp;
                bl[0][nt] = *(const half8*)(bp + 512);
            }
        }

        float4v acc[8][2] = {};

        #pragma unroll
        for (int ks = 0; ks < 8; ++ks) {
            const int cur = ks & 1, nxt = cur ^ 1;
            // prefetch next ks's B frags (global/L2) under this ks's MFMAs
            if (ks < 7) {
                #pragma unroll
                for (int nt = 0; nt < 2; ++nt) {
                    const _Float16* bp = e_frag + ((size_t)((ntbase + nt) * 8 + (ks + 1))) * 1024 + lane * 8;
                    bh[nxt][nt] = *(const half8*)bp;
                    bl[nxt][nt] = *(const half8*)(bp + 512);
                }
            }
            __builtin_amdgcn_s_setprio(1);
            #pragma unroll
            for (int mt = 0; mt < 8; ++mt) {
                const _Float16* ap = sA + (size_t)((mt * 8 + ks) * 2) * 512 + lane * 8;
                half8 ah = *(const half8*)ap;
                half8 al = *(const half8*)(ap + 512);
                #pragma unroll
                for (int nt = 0; nt < 2; ++nt) {
                    acc[mt][nt] = __builtin_amdgcn_mfma_f32_16x16x32_f16(ah, bh[cur][nt], acc[mt][nt], 0, 0, 0);
                    acc[mt][nt] = __builtin_amdgcn_mfma_f32_16x16x32_f16(ah, bl[cur][nt], acc[mt][nt], 0, 0, 0);
                    acc[mt][nt] = __builtin_amdgcn_mfma_f32_16x16x32_f16(al, bh[cur][nt], acc[mt][nt], 0, 0, 0);
                }
            }
            __builtin_amdgcn_s_setprio(0);
        }

        // ---- pass epilogue: score = ||e||^2 - 2*dot; per-row argmin.
        // C/D layout: col = lane&15, row = quad*4 + reg.
        float nrm[2]; int cg[2];
        #pragma unroll
        for (int nt = 0; nt < 2; ++nt) {
            cg[nt]  = (ntbase + nt) * 16 + l15;
            nrm[nt] = s_nrm[cg[nt]];
        }
        #pragma unroll
        for (int mt = 0; mt < 8; ++mt) {
            #pragma unroll
            for (int r = 0; r < 4; ++r) {
                float bs = nrm[0] - 2.0f * acc[mt][0][r]; int bi = cg[0];
                float s1 = nrm[1] - 2.0f * acc[mt][1][r];
                if (s1 < bs) { bs = s1; bi = cg[1]; }   // ascending codes: strict <
                #pragma unroll
                for (int m = 1; m < 16; m <<= 1) {   // reduce the 16 l15 lanes (same row)
                    float s2 = __shfl_xor(bs, m, 64);
                    int   i2 = __shfl_xor(bi, m, 64);
                    if (s2 < bs || (s2 == bs && i2 < bi)) { bs = s2; bi = i2; }
                }
                if (l15 == 0) {
                    const int row = mt * 16 + quad * 4 + r;
                    if (pass == 0) {
                        float2 pr; pr.x = bs; pr.y = (float)bi;
                        s_best[row][w] = pr;
                    } else {
                        // running merge: later passes have strictly higher codes,
                        // so strict < keeps the lowest index on ties.
                        float2 pv = s_best[row][w];
                        if (bs < pv.x) {
                            float2 pr; pr.x = bs; pr.y = (float)bi;
                            s_best[row][w] = pr;
                        }
                    }
                }
            }
        }
    }
    __syncthreads();

    // ---- block reduce over 8 wave slots/row; write indices
    if (t < BM) {
        float2 p0 = s_best[t][0];
        float bs = p0.x, bi = p0.y;
        #pragma unroll
        for (int s = 1; s < 8; ++s) {
            float2 pv = s_best[t][s];
            if (pv.x < bs || (pv.x == bs && pv.y < bi)) { bs = pv.x; bi = pv.y; }
        }
        s_idx[t] = (int)bi;
        idxf[rowblk + t] = bi;
    }

    if (!fused_gather) return;
    __syncthreads();

    // ---- fused gather: 4 threads/row, 16 float4 each
    const float4v* emb4 = (const float4v*)emb;
    float4v* zq4 = (float4v*)zq;
    const int rr = t >> 2, cb = t & 3;
    const int code = s_idx[rr];
    #pragma unroll
    for (int i = 0; i < 16; ++i) {
        const int chunk = cb + i * 4;
        zq4[(size_t)(rowblk + rr) * 64 + chunk] = emb4[(size_t)code * 64 + chunk];
    }
}

// ---- fallback gather (only when e_frag had to live in d_out): wave per row
__global__ __launch_bounds__(256)
void vq_gather(const float* __restrict__ emb,
               const float* __restrict__ idxf,
               float* __restrict__ zq) {
    const int tid  = blockIdx.x * 256 + threadIdx.x;
    const int r    = tid >> 6;
    const int lane = tid & 63;
    const int idx  = (int)idxf[r];
    const float4* ep = (const float4*)(emb + (size_t)idx * DIM);
    ((float4*)(zq + (size_t)r * DIM))[lane] = ep[lane];
}

extern "C" void kernel_launch(void* const* d_in, const int* in_sizes, int n_in,
                              void* d_out, int out_size, void* d_ws, size_t ws_size,
                              hipStream_t stream) {
    const float* z   = (const float*)d_in[0];   // (64,32,32,256) fp32
    const float* emb = (const float*)d_in[1];   // (1024,256) fp32

    float* zq   = (float*)d_out;                        // output 0: 16,777,216 f
    float* idxf = zq + (size_t)N_ROWS * DIM;            // output 1: 65,536 f

    // scratch: e_norm (4 KB pad) + e_frag (1 MB)
    const size_t need = 4096 + (size_t)N_CODES * DIM * 2 * sizeof(_Float16);
    const int in_ws = (ws_size >= need);
    char* base = in_ws ? (char*)d_ws : (char*)d_out;    // fallback: zq area; then
                                                        // gather must be a later kernel
    float*    e_norm = (float*)base;
    _Float16* e_frag = (_Float16*)(base + 4096);

    vq_prep<<<N_CODES, 64, 0, stream>>>(emb, e_norm, e_frag);
    vq_main<<<NBLKS, 512, 0, stream>>>(z, e_frag, e_norm, emb, zq, idxf, in_ws);
    if (!in_ws)
        vq_gather<<<(N_ROWS * 64) / 256, 256, 0, stream>>>(emb, idxf, zq);
}

// Round 3
// 200.916 us; speedup vs baseline: 1.3874x; 1.3874x over previous
//
#include <hip/hip_runtime.h>

typedef _Float16 half8  __attribute__((ext_vector_type(8)));
typedef _Float16 half4  __attribute__((ext_vector_type(4)));
typedef float    float4v __attribute__((ext_vector_type(4)));
typedef float    float8v __attribute__((ext_vector_type(8)));

#define N_ROWS  65536   // 64*32*32
#define N_CODES 1024
#define DIM     256
#define BM      64      // rows per block
#define NBLKS   (N_ROWS / BM)   // 1024

// ---- prep: one wave per code. ||e||^2 and hi/lo f16 split written in MFMA
// B-fragment order: frag block b = nt*8 + ks holds 1024 halves: [hi 512][lo 512],
// chunk p = quad*16 + l15 -> code = nt*16+l15, k = ks*32 + quad*8 + j.
__global__ __launch_bounds__(64)
void vq_prep(const float* __restrict__ emb, float* __restrict__ e_norm,
             _Float16* __restrict__ e_frag) {
    const int c = blockIdx.x, lane = threadIdx.x;
    const int l15 = c & 15, nt = c >> 4;
    float4v v = ((const float4v*)(emb + (size_t)c * DIM))[lane];
    half4 h, l;
    float ss = 0.f;
    #pragma unroll
    for (int j = 0; j < 4; ++j) {
        float x = v[j];
        ss += x * x;
        _Float16 hh = (_Float16)x;
        h[j] = hh;
        l[j] = (_Float16)(x - (float)hh);
    }
    // this lane's 4 elements: k = lane*4 .. +3
    const int ks = lane >> 3, q = (lane >> 1) & 3, jb = (lane & 1) * 4;
    _Float16* p = e_frag + ((size_t)(nt * 8 + ks)) * 1024 + (q * 16 + l15) * 8 + jb;
    *(half4*)p = h;
    *(half4*)(p + 512) = l;
    #pragma unroll
    for (int m = 32; m >= 1; m >>= 1) ss += __shfl_xor(ss, m, 64);
    if (lane == 0) e_norm[c] = ss;
}

// ---- main: 256 threads (4 waves), BM=64 rows/block, full K in LDS (64 KB),
// ~71 KB LDS total -> 2 resident blocks/CU so staging/epilogue of one block
// overlaps compute of the other. Each wave: ALL 64 rows x 256 codes in
// 2 passes of 128 codes (acc[4][8] = 128 regs, 8 independent MFMA chains;
// hi/lo products issued as 3 separate nt-sweeps so the 3-deep dependent
// chain per acc has distance-8 independence). B-frags direct from L2.
__global__ __launch_bounds__(256, 2)
void vq_main(const float* __restrict__ z,
             const _Float16* __restrict__ e_frag,
             const float* __restrict__ e_norm,
             const float* __restrict__ emb,
             float* __restrict__ zq,
             float* __restrict__ idxf,
             int fused_gather) {
    __shared__ _Float16 sA[32 * 2 * 512];     // [mt*8+ks][hi|lo][512] = 64 KB (mt<4)
    __shared__ float    s_nrm[N_CODES];       // 4 KB
    __shared__ float2   s_best[BM][5];        // 4 wave slots + pad: 2.5 KB
    __shared__ int      s_idx[BM];

    const int t = threadIdx.x;
    const int w = t >> 6, lane = t & 63, quad = lane >> 4, l15 = lane & 15;
    const int rowblk = blockIdx.x * BM;

    s_nrm[t]       = e_norm[t];
    s_nrm[t + 256] = e_norm[t + 256];
    s_nrm[t + 512] = e_norm[t + 512];
    s_nrm[t + 768] = e_norm[t + 768];

    // ---- stage A: wave w stages its mt=w tile (16 rows), all 8 ks slices.
    // Global: 16 rows x 32-col chunks (128 B/row). LDS write = fragbase +
    // lane*16 B, contiguous per wave: conflict-free.
    #pragma unroll
    for (int i = 0; i < 8; ++i) {
        const int row = w * 16 + l15;
        const int col = i * 32 + quad * 8;
        float8v v = *(const float8v*)(z + (size_t)(rowblk + row) * DIM + col);
        half8 h, lo;
        #pragma unroll
        for (int j = 0; j < 8; ++j) {
            float x = v[j];
            _Float16 hh = (_Float16)x;
            h[j] = hh;
            lo[j] = (_Float16)(x - (float)hh);
        }
        _Float16* p = sA + (size_t)((w * 8 + i) * 2) * 512 + lane * 8;
        *(half8*)p = h;
        *(half8*)(p + 512) = lo;
    }
    __syncthreads();   // the only compute barrier

    for (int pass = 0; pass < 2; ++pass) {
        const int ntbase = w * 16 + pass * 8;
        float4v acc[4][8] = {};

        #pragma unroll
        for (int ks = 0; ks < 8; ++ks) {
            // B frags for 8 nt tiles (hi+lo), direct from L2-resident e_frag
            half8 bh[8], bl[8];
            #pragma unroll
            for (int nt = 0; nt < 8; ++nt) {
                const _Float16* bp = e_frag + ((size_t)((ntbase + nt) * 8 + ks)) * 1024 + lane * 8;
                bh[nt] = *(const half8*)bp;
                bl[nt] = *(const half8*)(bp + 512);
            }
            __builtin_amdgcn_s_setprio(1);
            #pragma unroll
            for (int mt = 0; mt < 4; ++mt) {
                const _Float16* ap = sA + (size_t)((mt * 8 + ks) * 2) * 512 + lane * 8;
                half8 ah = *(const half8*)ap;
                half8 al = *(const half8*)(ap + 512);
                // three separate nt-sweeps: dep chains on each acc are
                // 3 deep but spaced 8 apart -> MFMA pipe stays fed
                #pragma unroll
                for (int nt = 0; nt < 8; ++nt)
                    acc[mt][nt] = __builtin_amdgcn_mfma_f32_16x16x32_f16(ah, bh[nt], acc[mt][nt], 0, 0, 0);
                #pragma unroll
                for (int nt = 0; nt < 8; ++nt)
                    acc[mt][nt] = __builtin_amdgcn_mfma_f32_16x16x32_f16(ah, bl[nt], acc[mt][nt], 0, 0, 0);
                #pragma unroll
                for (int nt = 0; nt < 8; ++nt)
                    acc[mt][nt] = __builtin_amdgcn_mfma_f32_16x16x32_f16(al, bh[nt], acc[mt][nt], 0, 0, 0);
            }
            __builtin_amdgcn_s_setprio(0);
        }

        // ---- pass epilogue: score = ||e||^2 - 2*dot; per-row argmin.
        // C/D layout: col = lane&15, row = quad*4 + reg.
        float nrm[8]; int cg[8];
        #pragma unroll
        for (int nt = 0; nt < 8; ++nt) {
            cg[nt]  = (ntbase + nt) * 16 + l15;
            nrm[nt] = s_nrm[cg[nt]];
        }
        #pragma unroll
        for (int mt = 0; mt < 4; ++mt) {
            #pragma unroll
            for (int r = 0; r < 4; ++r) {
                float bs = nrm[0] - 2.0f * acc[mt][0][r]; int bi = cg[0];
                #pragma unroll
                for (int nt = 1; nt < 8; ++nt) {
                    float s = nrm[nt] - 2.0f * acc[mt][nt][r];
                    if (s < bs) { bs = s; bi = cg[nt]; }   // ascending codes: strict <
                }
                #pragma unroll
                for (int m = 1; m < 16; m <<= 1) {   // reduce the 16 l15 lanes (same row)
                    float s2 = __shfl_xor(bs, m, 64);
                    int   i2 = __shfl_xor(bi, m, 64);
                    if (s2 < bs || (s2 == bs && i2 < bi)) { bs = s2; bi = i2; }
                }
                if (l15 == 0) {
                    const int row = mt * 16 + quad * 4 + r;
                    if (pass == 0) {
                        float2 pr; pr.x = bs; pr.y = (float)bi;
                        s_best[row][w] = pr;
                    } else {
                        // running merge: later pass has strictly higher codes,
                        // so strict < keeps the lowest index on ties.
                        float2 pv = s_best[row][w];
                        if (bs < pv.x) {
                            float2 pr; pr.x = bs; pr.y = (float)bi;
                            s_best[row][w] = pr;
                        }
                    }
                }
            }
        }
    }
    __syncthreads();

    // ---- block reduce over 4 wave slots/row; write indices
    if (t < BM) {
        float2 p0 = s_best[t][0];
        float bs = p0.x, bi = p0.y;
        #pragma unroll
        for (int s = 1; s < 4; ++s) {
            float2 pv = s_best[t][s];
            if (pv.x < bs || (pv.x == bs && pv.y < bi)) { bs = pv.x; bi = pv.y; }
        }
        s_idx[t] = (int)bi;
        idxf[rowblk + t] = bi;
    }

    if (!fused_gather) return;
    __syncthreads();

    // ---- fused gather: 4 threads/row, 16 float4 each (64 rows, 256 threads)
    const float4v* emb4 = (const float4v*)emb;
    float4v* zq4 = (float4v*)zq;
    const int rr = t >> 2, cb = t & 3;
    const int code = s_idx[rr];
    #pragma unroll
    for (int i = 0; i < 16; ++i) {
        const int chunk = cb + i * 4;
        zq4[(size_t)(rowblk + rr) * 64 + chunk] = emb4[(size_t)code * 64 + chunk];
    }
}

// ---- fallback gather (only when e_frag had to live in d_out): wave per row
__global__ __launch_bounds__(256)
void vq_gather(const float* __restrict__ emb,
               const float* __restrict__ idxf,
               float* __restrict__ zq) {
    const int tid  = blockIdx.x * 256 + threadIdx.x;
    const int r    = tid >> 6;
    const int lane = tid & 63;
    const int idx  = (int)idxf[r];
    const float4* ep = (const float4*)(emb + (size_t)idx * DIM);
    ((float4*)(zq + (size_t)r * DIM))[lane] = ep[lane];
}

extern "C" void kernel_launch(void* const* d_in, const int* in_sizes, int n_in,
                              void* d_out, int out_size, void* d_ws, size_t ws_size,
                              hipStream_t stream) {
    const float* z   = (const float*)d_in[0];   // (64,32,32,256) fp32
    const float* emb = (const float*)d_in[1];   // (1024,256) fp32

    float* zq   = (float*)d_out;                        // output 0: 16,777,216 f
    float* idxf = zq + (size_t)N_ROWS * DIM;            // output 1: 65,536 f

    // scratch: e_norm (4 KB pad) + e_frag (1 MB)
    const size_t need = 4096 + (size_t)N_CODES * DIM * 2 * sizeof(_Float16);
    const int in_ws = (ws_size >= need);
    char* base = in_ws ? (char*)d_ws : (char*)d_out;    // fallback: zq area; then
                                                        // gather must be a later kernel
    float*    e_norm = (float*)base;
    _Float16* e_frag = (_Float16*)(base + 4096);

    vq_prep<<<N_CODES, 64, 0, stream>>>(emb, e_norm, e_frag);
    vq_main<<<NBLKS, 256, 0, stream>>>(z, e_frag, e_norm, emb, zq, idxf, in_ws);
    if (!in_ws)
        vq_gather<<<(N_ROWS * 64) / 256, 256, 0, stream>>>(emb, idxf, zq);
}